// Round 8
// baseline (111.569 us; speedup 1.0000x reference)
//
#include <hip/hip_runtime.h>
#include <hip/hip_bf16.h>

// SubjectLayers via bf16 MFMA 32x32x16: out[b,o,t] = sum_c W[s,o,c]*x[b,c,t] + b[s,o]
// B=128, C=64, T=8192, S=16. fp32 in/out, bf16 matrix cores.
//
// R7 = R6 structure (all global access = row-contiguous bursts, LDS-decoupled
// fragment shapes, tile reused for output) with TT 256->128:
//   - LDS 33.8KB -> 4 blocks/CU (vs 2): 4-deep TLP hides each block's serial
//     load->compute->store chain (R6 post-mortem: chain ~3x memory floor).
//   - staging/store: one instr = 2 rows x 512B contiguous segments.

typedef __attribute__((ext_vector_type(8))) short  bf16x8;   // 4 VGPRs
typedef __attribute__((ext_vector_type(16))) float f32x16;   // 16 VGPRs

namespace {
constexpr int Cdim  = 64;
constexpr int Tdim  = 8192;
constexpr int TT    = 128;        // t per block tile
constexpr int STR   = TT + 4;     // LDS row stride in dwords (16B-aligned)
constexpr int BLOCK = 256;        // 4 waves
}

static __device__ __forceinline__ short f2bf(float f) {
    return (short)__builtin_bit_cast(unsigned short, __float2bfloat16(f));
}

__global__ __launch_bounds__(BLOCK, 4)
void subject_layers_r7(const float* __restrict__ x,
                       const int*   __restrict__ subj,
                       const float* __restrict__ W,
                       const float* __restrict__ bias,
                       float*       __restrict__ out) {
    __shared__ float tile[Cdim * STR];   // 33792 B; x-tile then reused as out-tile

    const int b    = blockIdx.y;
    const int tb   = blockIdx.x;
    const int tid  = threadIdx.x;
    const int wave = tid >> 6;
    const int lane = tid & 63;
    const int hi   = lane >> 5;   // 0..1
    const int ln   = lane & 31;   // m/n index within 32-tile
    const int s    = subj[b];

    const size_t xbase = (size_t)b * Cdim * Tdim + (size_t)tb * TT;

    // ---- stage x tile: one instr = 2 rows (row-pair), 512B contiguous each ----
    // pair index p (0..31): rows 2p, 2p+1. wave handles p = g*4 + wave, g<8.
    // lane -> row = 2p + (lane>>5), col = (lane&31)*4.
    {
        float4 v[4];
        #pragma unroll
        for (int gg = 0; gg < 2; ++gg) {   // batches of 4 pair-loads
            #pragma unroll
            for (int g = 0; g < 4; ++g) {
                const int p   = (gg * 4 + g) * 4 + wave;
                const int row = p * 2 + hi;
                v[g] = *reinterpret_cast<const float4*>(
                    x + xbase + (size_t)row * Tdim + ln * 4);
            }
            #pragma unroll
            for (int g = 0; g < 4; ++g) {
                const int p   = (gg * 4 + g) * 4 + wave;
                const int row = p * 2 + hi;
                *reinterpret_cast<float4*>(&tile[row * STR + ln * 4]) = v[g];
            }
        }
    }

    // ---- A fragments: W[s] -> bf16 (no dependency on staging) ----
    // A[m][k]: m = ln, k = kb*16 + hi*8 + j  (mirrored with B -> k-perm cancels)
    bf16x8 afrag[2][4];
    const float* Wb = W + (size_t)s * Cdim * Cdim;
    #pragma unroll
    for (int ot = 0; ot < 2; ++ot) {
        #pragma unroll
        for (int kb = 0; kb < 4; ++kb) {
            const float* ap = Wb + (size_t)(ot * 32 + ln) * Cdim + kb * 16 + hi * 8;
            const float4 a0 = *reinterpret_cast<const float4*>(ap);
            const float4 a1 = *reinterpret_cast<const float4*>(ap + 4);
            bf16x8 f;
            f[0] = f2bf(a0.x); f[1] = f2bf(a0.y); f[2] = f2bf(a0.z); f[3] = f2bf(a0.w);
            f[4] = f2bf(a1.x); f[5] = f2bf(a1.y); f[6] = f2bf(a1.z); f[7] = f2bf(a1.w);
            afrag[ot][kb] = f;
        }
    }

    // ---- bias -> accumulator init ----
    // C/D: col = ln, row(reg r) = (r&3) + 8*(r>>2) + 4*hi   [m74/m101-verified]
    f32x16 bini[2];
    const float* bb = bias + (size_t)s * Cdim;
    #pragma unroll
    for (int ot = 0; ot < 2; ++ot)
        #pragma unroll
        for (int r = 0; r < 16; ++r)
            bini[ot][r] = bb[ot * 32 + (r & 3) + 8 * (r >> 2) + 4 * hi];

    __syncthreads();   // x tile ready

    // ---- B fragments: wave w owns cols [w*32, w*32+32) ----
    // B[k][n]: n = ln, k = kb*16 + hi*8 + j
    const int col = wave * 32 + ln;
    bf16x8 bfrag[4];
    #pragma unroll
    for (int kb = 0; kb < 4; ++kb) {
        bf16x8 f;
        #pragma unroll
        for (int j = 0; j < 8; ++j)
            f[j] = f2bf(tile[(kb * 16 + hi * 8 + j) * STR + col]);
        bfrag[kb] = f;
    }

    __syncthreads();   // all reads done; tile becomes the out-tile

    // ---- MFMA + epilogue into tile[o][col] ----
    #pragma unroll
    for (int ot = 0; ot < 2; ++ot) {
        f32x16 acc = bini[ot];
        #pragma unroll
        for (int kb = 0; kb < 4; ++kb)
            acc = __builtin_amdgcn_mfma_f32_32x32x16_bf16(afrag[ot][kb], bfrag[kb], acc, 0, 0, 0);
        #pragma unroll
        for (int r = 0; r < 16; ++r)
            tile[(ot * 32 + (r & 3) + 8 * (r >> 2) + 4 * hi) * STR + col] = acc[r];
    }

    __syncthreads();   // out tile complete

    // ---- cooperative store: same 2-rows-per-instr burst shape as the load ----
    #pragma unroll
    for (int g = 0; g < 8; ++g) {
        const int p   = g * 4 + wave;
        const int row = p * 2 + hi;
        const float4 v = *reinterpret_cast<const float4*>(&tile[row * STR + ln * 4]);
        *reinterpret_cast<float4*>(out + xbase + (size_t)row * Tdim + ln * 4) = v;
    }
}

extern "C" void kernel_launch(void* const* d_in, const int* in_sizes, int n_in,
                              void* d_out, int out_size, void* d_ws, size_t ws_size,
                              hipStream_t stream) {
    const float* x    = (const float*)d_in[0];   // [B, C, T]
    const int*   subj = (const int*)  d_in[1];   // [B]
    const float* W    = (const float*)d_in[2];   // [S, C, C]
    const float* bias = (const float*)d_in[3];   // [S, C]
    float*       out  = (float*)d_out;           // [B, C, T]

    const int B = in_sizes[1];                   // 128
    dim3 grid(Tdim / TT, B);                     // (64, 128) = 8192 blocks
    dim3 block(BLOCK);
    hipLaunchKernelGGL(subject_layers_r7, grid, block, 0, stream,
                       x, subj, W, bias, out);
}